// Round 4
// baseline (270.627 us; speedup 1.0000x reference)
//
#include <hip/hip_runtime.h>
#include <stdint.h>

#define BB 2
#define TT 2048
#define CC 1024
#define HH 16
#define DD 64
#define MM (BB*TT)   // 4096

typedef unsigned short u16;
typedef __attribute__((ext_vector_type(8))) short short8;
typedef __attribute__((ext_vector_type(4))) float float4v;
typedef __attribute__((ext_vector_type(4))) unsigned short ushort4v;

typedef const __attribute__((address_space(1))) void* gas_t;
typedef __attribute__((address_space(3))) void* las_t;

__device__ __forceinline__ u16 f2bf(float f) {
  union { float f; uint32_t u; } v; v.f = f;
  uint32_t u = v.u;
  return (u16)((u + 0x7FFFu + ((u >> 16) & 1)) >> 16);
}

__device__ __forceinline__ void gld_lds16(const void* g, void* l) {
  __builtin_amdgcn_global_load_lds((gas_t)g, (las_t)l, 16, 0, 0);
}

// ---------------- convert x (fp32 -> bf16) ----------------
__global__ __launch_bounds__(256) void k_convert_x(const float* __restrict__ x, u16* __restrict__ xb) {
  int i = (blockIdx.x * 256 + threadIdx.x) * 4;
  float4v v = *(const float4v*)(x + i);
  ushort4v o;
  o[0] = f2bf(v[0]); o[1] = f2bf(v[1]); o[2] = f2bf(v[2]); o[3] = f2bf(v[3]);
  *(ushort4v*)(xb + i) = o;
}

// ---------------- transpose weights (fp32 [k][n] -> bf16 [n][k]) ----------------
__global__ __launch_bounds__(256) void k_transpose_w(const float* __restrict__ Wq, const float* __restrict__ Wk,
                                                     const float* __restrict__ Wv, const float* __restrict__ Wo,
                                                     u16* __restrict__ WT) {
  __shared__ u16 tile[64][72];
  int which = blockIdx.y;
  const float* W = (which == 0) ? Wq : (which == 1) ? Wk : (which == 2) ? Wv : Wo;
  u16* out = WT + (size_t)which * CC * CC;
  int tr = (blockIdx.x >> 4) * 64, tc = (blockIdx.x & 15) * 64;
#pragma unroll
  for (int i = 0; i < 16; ++i) {
    int e = i * 256 + threadIdx.x;
    int r = e >> 6, c = e & 63;
    tile[r][c] = f2bf(W[(size_t)(tr + r) * CC + tc + c]);
  }
  __syncthreads();
#pragma unroll
  for (int i = 0; i < 16; ++i) {
    int e = i * 256 + threadIdx.x;
    int cc2 = e >> 6, rr = e & 63;
    out[(size_t)(tc + cc2) * CC + tr + rr] = tile[rr][cc2];
  }
}

// ---------------- QKV projection GEMM ----------------
// Y = xb[4096,1024] @ W + b ; writes Q/K as bf16 [b,h,t,d] (Q pre-scaled), V as bf16 [b,h,d,t]
__global__ __launch_bounds__(256, 2) void k_qkv_gemm(
    const u16* __restrict__ xb, const u16* __restrict__ WTall,
    const float* __restrict__ bq, const float* __restrict__ bk, const float* __restrict__ bv,
    u16* __restrict__ Qw, u16* __restrict__ Kw, u16* __restrict__ Vtw) {
  __shared__ u16 Al[2][128 * 32];
  __shared__ u16 Bl[2][128 * 32];
  int p = blockIdx.y;
  const u16* WT = WTall + (size_t)p * (CC * CC);
  const float* bias = (p == 0) ? bq : (p == 1) ? bk : bv;
  int m0 = (blockIdx.x >> 3) * 128;
  int n0 = (blockIdx.x & 7) * 128;
  int tid = threadIdx.x;
  int lane = tid & 63, wave = tid >> 6;
  int wr = wave >> 1, wc = wave & 1;

  float4v acc[4][4];
#pragma unroll
  for (int i = 0; i < 4; ++i)
#pragma unroll
    for (int j = 0; j < 4; ++j) acc[i][j] = float4v{0.f, 0.f, 0.f, 0.f};

  auto stage = [&](int buf, int kt) {
    int k0 = kt * 32;
#pragma unroll
    for (int it = 0; it < 2; ++it) {
      int fc = tid + it * 256;
      int r = fc >> 2, c = fc & 3;
      int cg = c ^ ((r >> 1) & 3);
      const u16* gA = xb + (size_t)(m0 + r) * CC + k0 + cg * 8;
      const u16* gB = WT + (size_t)(n0 + r) * CC + k0 + cg * 8;
      char* lA = (char*)&Al[buf][0] + (wave * 64 + it * 256) * 16;
      char* lB = (char*)&Bl[buf][0] + (wave * 64 + it * 256) * 16;
      gld_lds16(gA, lA);
      gld_lds16(gB, lB);
    }
  };

  stage(0, 0);
  __syncthreads();
  int buf = 0;
  for (int kt = 0; kt < 32; ++kt) {
    if (kt + 1 < 32) stage(buf ^ 1, kt + 1);
    short8 af[4], bfr[4];
#pragma unroll
    for (int mf = 0; mf < 4; ++mf) {
      int row = wr * 64 + mf * 16 + (lane & 15);
      int cs = (lane >> 4) ^ ((row >> 1) & 3);
      af[mf] = *(const short8*)((const char*)&Al[buf][0] + row * 64 + cs * 16);
    }
#pragma unroll
    for (int nf = 0; nf < 4; ++nf) {
      int row = wc * 64 + nf * 16 + (lane & 15);
      int cs = (lane >> 4) ^ ((row >> 1) & 3);
      bfr[nf] = *(const short8*)((const char*)&Bl[buf][0] + row * 64 + cs * 16);
    }
#pragma unroll
    for (int mf = 0; mf < 4; ++mf)
#pragma unroll
      for (int nf = 0; nf < 4; ++nf)
        acc[mf][nf] = __builtin_amdgcn_mfma_f32_16x16x32_bf16(af[mf], bfr[nf], acc[mf][nf], 0, 0, 0);
    __syncthreads();
    buf ^= 1;
  }

  // epilogue: Q scaled by 1/sqrt(d) * log2(e) so attention can use exp2
  const float QSCALE = 0.125f * 1.44269504088896340736f;
#pragma unroll
  for (int mf = 0; mf < 4; ++mf) {
#pragma unroll
    for (int nf = 0; nf < 4; ++nf) {
      int n = n0 + wc * 64 + nf * 16 + (lane & 15);
      float bval = bias[n];
      int rowBase = wr * 64 + mf * 16 + (lane >> 4) * 4;
      int m_ = m0 + rowBase;
      int b_ = m_ >> 11, t_ = m_ & 2047;
      int h_ = n >> 6, dd = n & 63;
      if (p == 2) {
        ushort4v pk;
#pragma unroll
        for (int i = 0; i < 4; ++i) pk[i] = f2bf(acc[mf][nf][i] + bval);
        *(ushort4v*)(Vtw + ((size_t)(b_ * HH + h_) * DD + dd) * TT + t_) = pk;
      } else {
        u16* outp = (p == 0) ? Qw : Kw;
        float s = (p == 0) ? QSCALE : 1.0f;
#pragma unroll
        for (int i = 0; i < 4; ++i) {
          outp[((size_t)(b_ * HH + h_) * TT + (t_ + i)) * DD + dd] = f2bf((acc[mf][nf][i] + bval) * s);
        }
      }
    }
  }
}

// ---------------- flash attention (causal), v3 ----------------
// v2 post-mortem: latency-bound — blocks round-robin XCDs so each XCD's L2
// needed 16 MB of K/V (32 heads) -> thrash, loads served from L3/HBM at
// ~600-900 cyc with only 2 waves/SIMD to hide it. v3: (1) XCD-aware decode
// (bid&7 -> xcd) groups each XCD onto 4 heads = 2 MB K+V, L2-resident;
// (2) register double-buffer prefetch of next tile's K/V fragments
// (statically indexed A/B bodies, rule #20) hides remaining L2 latency
// under QK/softmax/PV. Work balance as v2 (wave owns units u and 127-u).
__global__ __launch_bounds__(256, 2) void k_attn(
    const u16* __restrict__ Qw, const u16* __restrict__ Kw,
    const u16* __restrict__ Vtw, u16* __restrict__ Ow) {
  __shared__ u16 Pl[4][16 * 88];
  int l = blockIdx.x;
  int xcd = l & 7, slot = l >> 3;
  int bh = xcd + ((slot >> 4) << 3);   // XCD x serves heads {x, x+8, x+16, x+24}
  int qblk = slot & 15;
  int tid = threadIdx.x, lane = tid & 63, wave = tid >> 6;
  int u0 = qblk * 4 + wave;  // [0,64)
  const u16* Qbase = Qw + (size_t)bh * TT * DD;
  const u16* Kbase = Kw + (size_t)bh * TT * DD;
  const u16* Vbase = Vtw + (size_t)bh * DD * TT;
  int b_ = bh >> 4, h_ = bh & 15;
  u16* Pw = &Pl[wave][0];

  const u16* kp = Kbase + (size_t)(lane & 15) * DD + (lane >> 4) * 8;
  const u16* vp = Vbase + (size_t)(lane & 15) * TT + (lane >> 4) * 8;

#pragma unroll
  for (int ph = 0; ph < 2; ++ph) {
    int qu = ph ? (127 - u0) : u0;
    int qw = qu * 16;
    short8 qf[2];
#pragma unroll
    for (int kc = 0; kc < 2; ++kc)
      qf[kc] = *(const short8*)(Qbase + (size_t)(qw + (lane & 15)) * DD + kc * 32 + (lane >> 4) * 8);

    float4v accd[4];
    float mrun[4], lrun[4];
#pragma unroll
    for (int nf = 0; nf < 4; ++nf) accd[nf] = float4v{0.f, 0.f, 0.f, 0.f};
#pragma unroll
    for (int i = 0; i < 4; ++i) { mrun[i] = -1e30f; lrun[i] = 0.f; }

    int nt = (qw + 15) / 64 + 1;

    auto loadKV = [&](int t, short8 (&kf)[2][4], short8 (&vf)[2][4]) {
      int kv0 = t * 64;
#pragma unroll
      for (int kc = 0; kc < 2; ++kc)
#pragma unroll
        for (int nf = 0; nf < 4; ++nf) {
          kf[kc][nf] = *(const short8*)(kp + (size_t)(kv0 + nf * 16) * DD + kc * 32);
          vf[kc][nf] = *(const short8*)(vp + (size_t)(nf * 16) * TT + kv0 + kc * 32);
        }
    };

    auto tilebody = [&](int t, short8 (&kf)[2][4], short8 (&vf)[2][4]) {
      int kv0 = t * 64;
      float4v s[4];
#pragma unroll
      for (int nf = 0; nf < 4; ++nf) s[nf] = float4v{0.f, 0.f, 0.f, 0.f};
#pragma unroll
      for (int kc = 0; kc < 2; ++kc)
#pragma unroll
        for (int nf = 0; nf < 4; ++nf)
          s[nf] = __builtin_amdgcn_mfma_f32_16x16x32_bf16(qf[kc], kf[kc][nf], s[nf], 0, 0, 0);

      if (kv0 + 63 > qw) {
#pragma unroll
        for (int nf = 0; nf < 4; ++nf)
#pragma unroll
          for (int i = 0; i < 4; ++i) {
            int qg = qw + (lane >> 4) * 4 + i;
            int kg = kv0 + nf * 16 + (lane & 15);
            if (kg > qg) s[nf][i] = -1e30f;
          }
      }

      float pm[4];
#pragma unroll
      for (int i = 0; i < 4; ++i) {
        float v = fmaxf(fmaxf(s[0][i], s[1][i]), fmaxf(s[2][i], s[3][i]));
        v = fmaxf(v, __shfl_xor(v, 1));
        v = fmaxf(v, __shfl_xor(v, 2));
        v = fmaxf(v, __shfl_xor(v, 4));
        v = fmaxf(v, __shfl_xor(v, 8));
        pm[i] = v;
      }
      bool need = false;
#pragma unroll
      for (int i = 0; i < 4; ++i) need |= (pm[i] > mrun[i] + 8.f);
      if (__any(need)) {
#pragma unroll
        for (int i = 0; i < 4; ++i) {
          float mn = fmaxf(mrun[i], pm[i]);
          float sc = __builtin_exp2f(mrun[i] - mn);
          mrun[i] = mn;
          lrun[i] *= sc;
#pragma unroll
          for (int nf = 0; nf < 4; ++nf) accd[nf][i] *= sc;
        }
      }

      float rs[4] = {0.f, 0.f, 0.f, 0.f};
#pragma unroll
      for (int nf = 0; nf < 4; ++nf)
#pragma unroll
        for (int i = 0; i < 4; ++i) {
          float pv = __builtin_exp2f(s[nf][i] - mrun[i]);
          rs[i] += pv;
          Pw[((lane >> 4) * 4 + i) * 88 + nf * 16 + (lane & 15)] = f2bf(pv);
        }
#pragma unroll
      for (int i = 0; i < 4; ++i) {
        float r = rs[i];
        r += __shfl_xor(r, 1);
        r += __shfl_xor(r, 2);
        r += __shfl_xor(r, 4);
        r += __shfl_xor(r, 8);
        lrun[i] += r;
      }

#pragma unroll
      for (int kc = 0; kc < 2; ++kc) {
        short8 pf = *(const short8*)((const char*)Pw + (lane & 15) * 176 + kc * 64 + (lane >> 4) * 16);
#pragma unroll
        for (int nf = 0; nf < 4; ++nf)
          accd[nf] = __builtin_amdgcn_mfma_f32_16x16x32_bf16(pf, vf[kc][nf], accd[nf], 0, 0, 0);
      }
    };

    // software pipeline: prefetch tile t+1 into the alternate register
    // buffer while computing tile t (all buffer refs statically indexed)
    short8 kfa[2][4], vfa[2][4], kfb[2][4], vfb[2][4];
    loadKV(0, kfa, vfa);
    for (int t = 0; t < nt; t += 2) {
      if (t + 1 < nt) loadKV(t + 1, kfb, vfb);
      tilebody(t, kfa, vfa);
      if (t + 1 < nt) {
        if (t + 2 < nt) loadKV(t + 2, kfa, vfa);
        tilebody(t + 1, kfb, vfb);
      }
    }

    // write out this q-unit
#pragma unroll
    for (int i = 0; i < 4; ++i) {
      float inv = 1.f / lrun[i];
      int t_ = qw + (lane >> 4) * 4 + i;
#pragma unroll
      for (int nf = 0; nf < 4; ++nf) {
        int dd = nf * 16 + (lane & 15);
        Ow[((size_t)(b_ * TT + t_)) * CC + h_ * DD + dd] = f2bf(accd[nf][i] * inv);
      }
    }
  }
}

// ---------------- output projection GEMM (bf16 in, fp32 out) ----------------
__global__ __launch_bounds__(256, 2) void k_out_gemm(
    const u16* __restrict__ Ob, const u16* __restrict__ WoT,
    const float* __restrict__ bo, float* __restrict__ out) {
  __shared__ u16 Al[2][128 * 32];
  __shared__ u16 Bl[2][128 * 32];
  int m0 = (blockIdx.x >> 3) * 128;
  int n0 = (blockIdx.x & 7) * 128;
  int tid = threadIdx.x;
  int lane = tid & 63, wave = tid >> 6;
  int wr = wave >> 1, wc = wave & 1;

  float4v acc[4][4];
#pragma unroll
  for (int i = 0; i < 4; ++i)
#pragma unroll
    for (int j = 0; j < 4; ++j) acc[i][j] = float4v{0.f, 0.f, 0.f, 0.f};

  auto stage = [&](int buf, int kt) {
    int k0 = kt * 32;
#pragma unroll
    for (int it = 0; it < 2; ++it) {
      int fc = tid + it * 256;
      int r = fc >> 2, c = fc & 3;
      int cg = c ^ ((r >> 1) & 3);
      const u16* gA = Ob + (size_t)(m0 + r) * CC + k0 + cg * 8;
      const u16* gB = WoT + (size_t)(n0 + r) * CC + k0 + cg * 8;
      char* lA = (char*)&Al[buf][0] + (wave * 64 + it * 256) * 16;
      char* lB = (char*)&Bl[buf][0] + (wave * 64 + it * 256) * 16;
      gld_lds16(gA, lA);
      gld_lds16(gB, lB);
    }
  };

  stage(0, 0);
  __syncthreads();
  int buf = 0;
  for (int kt = 0; kt < 32; ++kt) {
    if (kt + 1 < 32) stage(buf ^ 1, kt + 1);
    short8 af[4], bfr[4];
#pragma unroll
    for (int mf = 0; mf < 4; ++mf) {
      int row = wr * 64 + mf * 16 + (lane & 15);
      int cs = (lane >> 4) ^ ((row >> 1) & 3);
      af[mf] = *(const short8*)((const char*)&Al[buf][0] + row * 64 + cs * 16);
    }
#pragma unroll
    for (int nf = 0; nf < 4; ++nf) {
      int row = wc * 64 + nf * 16 + (lane & 15);
      int cs = (lane >> 4) ^ ((row >> 1) & 3);
      bfr[nf] = *(const short8*)((const char*)&Bl[buf][0] + row * 64 + cs * 16);
    }
#pragma unroll
    for (int mf = 0; mf < 4; ++mf)
#pragma unroll
      for (int nf = 0; nf < 4; ++nf)
        acc[mf][nf] = __builtin_amdgcn_mfma_f32_16x16x32_bf16(af[mf], bfr[nf], acc[mf][nf], 0, 0, 0);
    __syncthreads();
    buf ^= 1;
  }

#pragma unroll
  for (int mf = 0; mf < 4; ++mf)
#pragma unroll
    for (int nf = 0; nf < 4; ++nf) {
      int n = n0 + wc * 64 + nf * 16 + (lane & 15);
      float bval = bo[n];
      int rowBase = m0 + wr * 64 + mf * 16 + (lane >> 4) * 4;
#pragma unroll
      for (int i = 0; i < 4; ++i)
        out[(size_t)(rowBase + i) * CC + n] = acc[mf][nf][i] + bval;
    }
}

extern "C" void kernel_launch(void* const* d_in, const int* in_sizes, int n_in,
                              void* d_out, int out_size, void* d_ws, size_t ws_size,
                              hipStream_t stream) {
  const float* x  = (const float*)d_in[0];
  const float* Wq = (const float*)d_in[1];
  const float* bq = (const float*)d_in[2];
  const float* Wk = (const float*)d_in[3];
  const float* bk = (const float*)d_in[4];
  const float* Wv = (const float*)d_in[5];
  const float* bv = (const float*)d_in[6];
  const float* Wo = (const float*)d_in[7];
  const float* bo = (const float*)d_in[8];
  float* out = (float*)d_out;
  char* ws = (char*)d_ws;
  if (ws_size < (size_t)50331648) return;  // need 48 MB scratch

  u16* xb  = (u16*)(ws);                    // 8 MB
  u16* WT  = (u16*)(ws + 8388608);          // 4 x 2 MB (WqT,WkT,WvT,WoT)
  u16* Qw  = (u16*)(ws + 16777216);         // 8 MB  [b,h,t,d]
  u16* Kw  = (u16*)(ws + 25165824);         // 8 MB  [b,h,t,d]
  u16* Vtw = (u16*)(ws + 33554432);         // 8 MB  [b,h,d,t]
  u16* Ob  = (u16*)(ws + 41943040);         // 8 MB  [b*t, c]

  hipLaunchKernelGGL(k_convert_x, dim3(4096), dim3(256), 0, stream, x, xb);
  hipLaunchKernelGGL(k_transpose_w, dim3(256, 4), dim3(256), 0, stream, Wq, Wk, Wv, Wo, WT);
  hipLaunchKernelGGL(k_qkv_gemm, dim3(256, 3), dim3(256), 0, stream,
                     xb, WT, bq, bk, bv, Qw, Kw, Vtw);
  hipLaunchKernelGGL(k_attn, dim3(512), dim3(256), 0, stream, Qw, Kw, Vtw, Ob);
  hipLaunchKernelGGL(k_out_gemm, dim3(256), dim3(256), 0, stream,
                     Ob, WT + 3 * 1048576, bo, out);
}

// Round 5
// 268.362 us; speedup vs baseline: 1.0084x; 1.0084x over previous
//
#include <hip/hip_runtime.h>
#include <stdint.h>

#define BB 2
#define TT 2048
#define CC 1024
#define HH 16
#define DD 64
#define MM (BB*TT)   // 4096

typedef unsigned short u16;
typedef __attribute__((ext_vector_type(8))) short short8;
typedef __attribute__((ext_vector_type(4))) float float4v;
typedef __attribute__((ext_vector_type(4))) unsigned short ushort4v;

typedef const __attribute__((address_space(1))) void* gas_t;
typedef __attribute__((address_space(3))) void* las_t;

__device__ __forceinline__ u16 f2bf(float f) {
  union { float f; uint32_t u; } v; v.f = f;
  uint32_t u = v.u;
  return (u16)((u + 0x7FFFu + ((u >> 16) & 1)) >> 16);
}

__device__ __forceinline__ void gld_lds16(const void* g, void* l) {
  __builtin_amdgcn_global_load_lds((gas_t)g, (las_t)l, 16, 0, 0);
}

// ---------------- convert x (fp32 -> bf16) ----------------
__global__ __launch_bounds__(256) void k_convert_x(const float* __restrict__ x, u16* __restrict__ xb) {
  int i = (blockIdx.x * 256 + threadIdx.x) * 4;
  float4v v = *(const float4v*)(x + i);
  ushort4v o;
  o[0] = f2bf(v[0]); o[1] = f2bf(v[1]); o[2] = f2bf(v[2]); o[3] = f2bf(v[3]);
  *(ushort4v*)(xb + i) = o;
}

// ---------------- transpose weights (fp32 [k][n] -> bf16 [n][k]) ----------------
__global__ __launch_bounds__(256) void k_transpose_w(const float* __restrict__ Wq, const float* __restrict__ Wk,
                                                     const float* __restrict__ Wv, const float* __restrict__ Wo,
                                                     u16* __restrict__ WT) {
  __shared__ u16 tile[64][72];
  int which = blockIdx.y;
  const float* W = (which == 0) ? Wq : (which == 1) ? Wk : (which == 2) ? Wv : Wo;
  u16* out = WT + (size_t)which * CC * CC;
  int tr = (blockIdx.x >> 4) * 64, tc = (blockIdx.x & 15) * 64;
#pragma unroll
  for (int i = 0; i < 16; ++i) {
    int e = i * 256 + threadIdx.x;
    int r = e >> 6, c = e & 63;
    tile[r][c] = f2bf(W[(size_t)(tr + r) * CC + tc + c]);
  }
  __syncthreads();
#pragma unroll
  for (int i = 0; i < 16; ++i) {
    int e = i * 256 + threadIdx.x;
    int cc2 = e >> 6, rr = e & 63;
    out[(size_t)(tc + cc2) * CC + tr + rr] = tile[rr][cc2];
  }
}

// ---------------- QKV projection GEMM ----------------
// Y = xb[4096,1024] @ W + b ; writes Q/K as bf16 [b,h,t,d] (Q pre-scaled), V as bf16 [b,h,d,t]
__global__ __launch_bounds__(256, 2) void k_qkv_gemm(
    const u16* __restrict__ xb, const u16* __restrict__ WTall,
    const float* __restrict__ bq, const float* __restrict__ bk, const float* __restrict__ bv,
    u16* __restrict__ Qw, u16* __restrict__ Kw, u16* __restrict__ Vtw) {
  __shared__ u16 Al[2][128 * 32];
  __shared__ u16 Bl[2][128 * 32];
  int p = blockIdx.y;
  const u16* WT = WTall + (size_t)p * (CC * CC);
  const float* bias = (p == 0) ? bq : (p == 1) ? bk : bv;
  int m0 = (blockIdx.x >> 3) * 128;
  int n0 = (blockIdx.x & 7) * 128;
  int tid = threadIdx.x;
  int lane = tid & 63, wave = tid >> 6;
  int wr = wave >> 1, wc = wave & 1;

  float4v acc[4][4];
#pragma unroll
  for (int i = 0; i < 4; ++i)
#pragma unroll
    for (int j = 0; j < 4; ++j) acc[i][j] = float4v{0.f, 0.f, 0.f, 0.f};

  auto stage = [&](int buf, int kt) {
    int k0 = kt * 32;
#pragma unroll
    for (int it = 0; it < 2; ++it) {
      int fc = tid + it * 256;
      int r = fc >> 2, c = fc & 3;
      int cg = c ^ ((r >> 1) & 3);
      const u16* gA = xb + (size_t)(m0 + r) * CC + k0 + cg * 8;
      const u16* gB = WT + (size_t)(n0 + r) * CC + k0 + cg * 8;
      char* lA = (char*)&Al[buf][0] + (wave * 64 + it * 256) * 16;
      char* lB = (char*)&Bl[buf][0] + (wave * 64 + it * 256) * 16;
      gld_lds16(gA, lA);
      gld_lds16(gB, lB);
    }
  };

  stage(0, 0);
  __syncthreads();
  int buf = 0;
  for (int kt = 0; kt < 32; ++kt) {
    if (kt + 1 < 32) stage(buf ^ 1, kt + 1);
    short8 af[4], bfr[4];
#pragma unroll
    for (int mf = 0; mf < 4; ++mf) {
      int row = wr * 64 + mf * 16 + (lane & 15);
      int cs = (lane >> 4) ^ ((row >> 1) & 3);
      af[mf] = *(const short8*)((const char*)&Al[buf][0] + row * 64 + cs * 16);
    }
#pragma unroll
    for (int nf = 0; nf < 4; ++nf) {
      int row = wc * 64 + nf * 16 + (lane & 15);
      int cs = (lane >> 4) ^ ((row >> 1) & 3);
      bfr[nf] = *(const short8*)((const char*)&Bl[buf][0] + row * 64 + cs * 16);
    }
#pragma unroll
    for (int mf = 0; mf < 4; ++mf)
#pragma unroll
      for (int nf = 0; nf < 4; ++nf)
        acc[mf][nf] = __builtin_amdgcn_mfma_f32_16x16x32_bf16(af[mf], bfr[nf], acc[mf][nf], 0, 0, 0);
    __syncthreads();
    buf ^= 1;
  }

  // epilogue: Q scaled by 1/sqrt(d) * log2(e) so attention can use exp2
  const float QSCALE = 0.125f * 1.44269504088896340736f;
#pragma unroll
  for (int mf = 0; mf < 4; ++mf) {
#pragma unroll
    for (int nf = 0; nf < 4; ++nf) {
      int n = n0 + wc * 64 + nf * 16 + (lane & 15);
      float bval = bias[n];
      int rowBase = wr * 64 + mf * 16 + (lane >> 4) * 4;
      int m_ = m0 + rowBase;
      int b_ = m_ >> 11, t_ = m_ & 2047;
      int h_ = n >> 6, dd = n & 63;
      if (p == 2) {
        ushort4v pk;
#pragma unroll
        for (int i = 0; i < 4; ++i) pk[i] = f2bf(acc[mf][nf][i] + bval);
        *(ushort4v*)(Vtw + ((size_t)(b_ * HH + h_) * DD + dd) * TT + t_) = pk;
      } else {
        u16* outp = (p == 0) ? Qw : Kw;
        float s = (p == 0) ? QSCALE : 1.0f;
#pragma unroll
        for (int i = 0; i < 4; ++i) {
          outp[((size_t)(b_ * HH + h_) * TT + (t_ + i)) * DD + dd] = f2bf((acc[mf][nf][i] + bval) * s);
        }
      }
    }
  }
}

// ---------------- flash attention (causal), v4 ----------------
// v3 post-mortem: latency-chain bound (FETCH fixed 10x, time unchanged).
// v4: (a) swapped MFMA operands: S = mfma(K,Q), O = mfma(Vt,P) -> softmax
// row lives at q=lane&15: local 16-val max/sum trees + only 2 shfl hops
// (was 8), rescale/m/l/normalize lane-local, P written as 4x ds_write_b64
// into XOR-swizzled per-wave LDS. (b) split-KV: waves (j, j+4) each do half
// of units (u,127-u) -> 4096 balanced waves (~17 tiles) = 4 waves/SIMD;
// lane-local merge via LDS + 2 barriers/job. K/V single-buffered in regs
// to stay <=128 VGPR. XCD decode kept (K/V L2-resident per round-4 FETCH).
__global__ __launch_bounds__(512, 4) void k_attn(
    const u16* __restrict__ Qw, const u16* __restrict__ Kw,
    const u16* __restrict__ Vtw, u16* __restrict__ Ow) {
  __shared__ u16 Pl[8][16 * 64];          // per-wave P buffer (swizzled)
  __shared__ float4v Accl[4][64][5];      // acc partials (+1 pad)
  __shared__ float Ml[4][64][2];          // m,l partials
  int l = blockIdx.x;
  int xcd = l & 7, slot = l >> 3;
  int bh = xcd + ((slot >> 4) << 3);      // XCD x serves heads {x,x+8,x+16,x+24}
  int qblk = slot & 15;
  int tid = threadIdx.x, lane = tid & 63, wave = tid >> 6;
  int j = wave & 3, half = wave >> 2;
  const u16* Qbase = Qw + (size_t)bh * TT * DD;
  const u16* Kbase = Kw + (size_t)bh * TT * DD;
  const u16* Vbase = Vtw + (size_t)bh * DD * TT;
  int b_ = bh >> 4, h_ = bh & 15;
  u16* Pw = &Pl[wave][0];
  int q15 = lane & 15, g = lane >> 4;
  int swz = (q15 & 7) << 4;

  const u16* kp = Kbase + (size_t)q15 * DD + g * 8;
  const u16* vp = Vbase + (size_t)q15 * TT + g * 8;

  for (int job = 0; job < 2; ++job) {
    int base_u = qblk * 4 + j;
    int qu = job ? (127 - base_u) : base_u;
    int qw = qu * 16;
    int nt = (qu >> 2) + 1;
    int t0 = half ? (nt >> 1) : 0;
    int t1 = half ? nt : (nt >> 1);

    short8 qf[2];
#pragma unroll
    for (int kc = 0; kc < 2; ++kc)
      qf[kc] = *(const short8*)(Qbase + (size_t)(qw + q15) * DD + kc * 32 + g * 8);

    float4v accd[4];
    float mrun = -1e30f, lrun = 0.f;
#pragma unroll
    for (int nf = 0; nf < 4; ++nf) accd[nf] = float4v{0.f, 0.f, 0.f, 0.f};

    for (int t = t0; t < t1; ++t) {
      int kv0 = t * 64;
      short8 kf[2][4], vf[2][4];
#pragma unroll
      for (int kc = 0; kc < 2; ++kc)
#pragma unroll
        for (int nf = 0; nf < 4; ++nf) {
          kf[kc][nf] = *(const short8*)(kp + (size_t)(kv0 + nf * 16) * DD + kc * 32);
          vf[kc][nf] = *(const short8*)(vp + (size_t)(nf * 16) * TT + kv0 + kc * 32);
        }

      // S = K * Q^T : lane holds q = lane&15, k = kv0 + nf*16 + g*4 + i
      float4v s[4];
#pragma unroll
      for (int nf = 0; nf < 4; ++nf) s[nf] = float4v{0.f, 0.f, 0.f, 0.f};
#pragma unroll
      for (int kc = 0; kc < 2; ++kc)
#pragma unroll
        for (int nf = 0; nf < 4; ++nf)
          s[nf] = __builtin_amdgcn_mfma_f32_16x16x32_bf16(kf[kc][nf], qf[kc], s[nf], 0, 0, 0);

      if (kv0 + 63 > qw) {
        int qg = qw + q15;
#pragma unroll
        for (int nf = 0; nf < 4; ++nf)
#pragma unroll
          for (int i = 0; i < 4; ++i) {
            int kg = kv0 + nf * 16 + g * 4 + i;
            if (kg > qg) s[nf][i] = -1e30f;
          }
      }

      // row max: local tree over 16 values + 2 shfl hops
      float pm = -1e30f;
#pragma unroll
      for (int nf = 0; nf < 4; ++nf) {
        float a = fmaxf(fmaxf(s[nf][0], s[nf][1]), fmaxf(s[nf][2], s[nf][3]));
        pm = fmaxf(pm, a);
      }
      pm = fmaxf(pm, __shfl_xor(pm, 16));
      pm = fmaxf(pm, __shfl_xor(pm, 32));

      // defer-max (T13): rescale only when some row grew past threshold
      if (__any(pm > mrun + 8.f)) {
        float mn = fmaxf(mrun, pm);
        float sc = __builtin_exp2f(mrun - mn);
        mrun = mn;
        lrun *= sc;
#pragma unroll
        for (int nf = 0; nf < 4; ++nf)
#pragma unroll
          for (int i = 0; i < 4; ++i) accd[nf][i] *= sc;
      }

      // P = exp2(S - m): lane-local; pack 4 bf16 -> one ds_write_b64 per nf
      float rs = 0.f;
#pragma unroll
      for (int nf = 0; nf < 4; ++nf) {
        ushort4v pk;
#pragma unroll
        for (int i = 0; i < 4; ++i) {
          float pv = __builtin_exp2f(s[nf][i] - mrun);
          rs += pv;
          pk[i] = f2bf(pv);
        }
        *(ushort4v*)((char*)Pw + q15 * 128 + ((nf * 32 + g * 8) ^ swz)) = pk;
      }
      rs += __shfl_xor(rs, 16);
      rs += __shfl_xor(rs, 32);
      lrun += rs;

      // O += Vt * P : lane holds q = lane&15, d = nf*16 + g*4 + i
#pragma unroll
      for (int kc = 0; kc < 2; ++kc) {
        short8 pf = *(const short8*)((const char*)Pw + q15 * 128 + ((kc * 64 + g * 16) ^ swz));
#pragma unroll
        for (int nf = 0; nf < 4; ++nf)
          accd[nf] = __builtin_amdgcn_mfma_f32_16x16x32_bf16(vf[kc][nf], pf, accd[nf], 0, 0, 0);
      }
    }

    // merge halves: upper wave publishes, lower wave combines + writes
    if (half) {
      Ml[j][lane][0] = mrun;
      Ml[j][lane][1] = lrun;
#pragma unroll
      for (int nf = 0; nf < 4; ++nf) Accl[j][lane][nf] = accd[nf];
    }
    __syncthreads();
    if (!half) {
      float m1 = Ml[j][lane][0], l1 = Ml[j][lane][1];
      float mn = fmaxf(mrun, m1);
      float s0 = __builtin_exp2f(mrun - mn);
      float s1 = __builtin_exp2f(m1 - mn);
      float inv = 1.f / (lrun * s0 + l1 * s1);
#pragma unroll
      for (int nf = 0; nf < 4; ++nf) {
        float4v a1 = Accl[j][lane][nf];
        ushort4v pk;
#pragma unroll
        for (int i = 0; i < 4; ++i)
          pk[i] = f2bf((accd[nf][i] * s0 + a1[i] * s1) * inv);
        *(ushort4v*)(Ow + ((size_t)(b_ * TT + qw + q15)) * CC + h_ * DD + nf * 16 + g * 4) = pk;
      }
    }
    __syncthreads();
  }
}

// ---------------- output projection GEMM (bf16 in, fp32 out) ----------------
__global__ __launch_bounds__(256, 2) void k_out_gemm(
    const u16* __restrict__ Ob, const u16* __restrict__ WoT,
    const float* __restrict__ bo, float* __restrict__ out) {
  __shared__ u16 Al[2][128 * 32];
  __shared__ u16 Bl[2][128 * 32];
  int m0 = (blockIdx.x >> 3) * 128;
  int n0 = (blockIdx.x & 7) * 128;
  int tid = threadIdx.x;
  int lane = tid & 63, wave = tid >> 6;
  int wr = wave >> 1, wc = wave & 1;

  float4v acc[4][4];
#pragma unroll
  for (int i = 0; i < 4; ++i)
#pragma unroll
    for (int j = 0; j < 4; ++j) acc[i][j] = float4v{0.f, 0.f, 0.f, 0.f};

  auto stage = [&](int buf, int kt) {
    int k0 = kt * 32;
#pragma unroll
    for (int it = 0; it < 2; ++it) {
      int fc = tid + it * 256;
      int r = fc >> 2, c = fc & 3;
      int cg = c ^ ((r >> 1) & 3);
      const u16* gA = Ob + (size_t)(m0 + r) * CC + k0 + cg * 8;
      const u16* gB = WoT + (size_t)(n0 + r) * CC + k0 + cg * 8;
      char* lA = (char*)&Al[buf][0] + (wave * 64 + it * 256) * 16;
      char* lB = (char*)&Bl[buf][0] + (wave * 64 + it * 256) * 16;
      gld_lds16(gA, lA);
      gld_lds16(gB, lB);
    }
  };

  stage(0, 0);
  __syncthreads();
  int buf = 0;
  for (int kt = 0; kt < 32; ++kt) {
    if (kt + 1 < 32) stage(buf ^ 1, kt + 1);
    short8 af[4], bfr[4];
#pragma unroll
    for (int mf = 0; mf < 4; ++mf) {
      int row = wr * 64 + mf * 16 + (lane & 15);
      int cs = (lane >> 4) ^ ((row >> 1) & 3);
      af[mf] = *(const short8*)((const char*)&Al[buf][0] + row * 64 + cs * 16);
    }
#pragma unroll
    for (int nf = 0; nf < 4; ++nf) {
      int row = wc * 64 + nf * 16 + (lane & 15);
      int cs = (lane >> 4) ^ ((row >> 1) & 3);
      bfr[nf] = *(const short8*)((const char*)&Bl[buf][0] + row * 64 + cs * 16);
    }
#pragma unroll
    for (int mf = 0; mf < 4; ++mf)
#pragma unroll
      for (int nf = 0; nf < 4; ++nf)
        acc[mf][nf] = __builtin_amdgcn_mfma_f32_16x16x32_bf16(af[mf], bfr[nf], acc[mf][nf], 0, 0, 0);
    __syncthreads();
    buf ^= 1;
  }

#pragma unroll
  for (int mf = 0; mf < 4; ++mf)
#pragma unroll
    for (int nf = 0; nf < 4; ++nf) {
      int n = n0 + wc * 64 + nf * 16 + (lane & 15);
      float bval = bo[n];
      int rowBase = m0 + wr * 64 + mf * 16 + (lane >> 4) * 4;
#pragma unroll
      for (int i = 0; i < 4; ++i)
        out[(size_t)(rowBase + i) * CC + n] = acc[mf][nf][i] + bval;
    }
}

extern "C" void kernel_launch(void* const* d_in, const int* in_sizes, int n_in,
                              void* d_out, int out_size, void* d_ws, size_t ws_size,
                              hipStream_t stream) {
  const float* x  = (const float*)d_in[0];
  const float* Wq = (const float*)d_in[1];
  const float* bq = (const float*)d_in[2];
  const float* Wk = (const float*)d_in[3];
  const float* bk = (const float*)d_in[4];
  const float* Wv = (const float*)d_in[5];
  const float* bv = (const float*)d_in[6];
  const float* Wo = (const float*)d_in[7];
  const float* bo = (const float*)d_in[8];
  float* out = (float*)d_out;
  char* ws = (char*)d_ws;
  if (ws_size < (size_t)50331648) return;  // need 48 MB scratch

  u16* xb  = (u16*)(ws);                    // 8 MB
  u16* WT  = (u16*)(ws + 8388608);          // 4 x 2 MB (WqT,WkT,WvT,WoT)
  u16* Qw  = (u16*)(ws + 16777216);         // 8 MB  [b,h,t,d]
  u16* Kw  = (u16*)(ws + 25165824);         // 8 MB  [b,h,t,d]
  u16* Vtw = (u16*)(ws + 33554432);         // 8 MB  [b,h,d,t]
  u16* Ob  = (u16*)(ws + 41943040);         // 8 MB  [b*t, c]

  hipLaunchKernelGGL(k_convert_x, dim3(4096), dim3(256), 0, stream, x, xb);
  hipLaunchKernelGGL(k_transpose_w, dim3(256, 4), dim3(256), 0, stream, Wq, Wk, Wv, Wo, WT);
  hipLaunchKernelGGL(k_qkv_gemm, dim3(256, 3), dim3(256), 0, stream,
                     xb, WT, bq, bk, bv, Qw, Kw, Vtw);
  hipLaunchKernelGGL(k_attn, dim3(512), dim3(512), 0, stream, Qw, Kw, Vtw, Ob);
  hipLaunchKernelGGL(k_out_gemm, dim3(256), dim3(256), 0, stream,
                     Ob, WT + 3 * 1048576, bo, out);
}

// Round 6
// 204.625 us; speedup vs baseline: 1.3226x; 1.3115x over previous
//
#include <hip/hip_runtime.h>
#include <stdint.h>

#define BB 2
#define TT 2048
#define CC 1024
#define HH 16
#define DD 64
#define MM (BB*TT)   // 4096

typedef unsigned short u16;
typedef __attribute__((ext_vector_type(8))) short short8;
typedef __attribute__((ext_vector_type(4))) float float4v;
typedef __attribute__((ext_vector_type(16))) float f32x16;
typedef __attribute__((ext_vector_type(4))) unsigned short ushort4v;

typedef const __attribute__((address_space(1))) void* gas_t;
typedef __attribute__((address_space(3))) void* las_t;

__device__ __forceinline__ u16 f2bf(float f) {
  union { float f; uint32_t u; } v; v.f = f;
  uint32_t u = v.u;
  return (u16)((u + 0x7FFFu + ((u >> 16) & 1)) >> 16);
}

__device__ __forceinline__ uint32_t cvtpk(float lo, float hi) {
  uint32_t r;
  asm("v_cvt_pk_bf16_f32 %0, %1, %2" : "=v"(r) : "v"(lo), "v"(hi));
  return r;
}

__device__ __forceinline__ void gld_lds16(const void* g, void* l) {
  __builtin_amdgcn_global_load_lds((gas_t)g, (las_t)l, 16, 0, 0);
}

// ---------------- convert x (fp32 -> bf16) ----------------
__global__ __launch_bounds__(256) void k_convert_x(const float* __restrict__ x, u16* __restrict__ xb) {
  int i = (blockIdx.x * 256 + threadIdx.x) * 4;
  float4v v = *(const float4v*)(x + i);
  ushort4v o;
  o[0] = f2bf(v[0]); o[1] = f2bf(v[1]); o[2] = f2bf(v[2]); o[3] = f2bf(v[3]);
  *(ushort4v*)(xb + i) = o;
}

// ---------------- transpose weights (fp32 [k][n] -> bf16 [n][k]) ----------------
__global__ __launch_bounds__(256) void k_transpose_w(const float* __restrict__ Wq, const float* __restrict__ Wk,
                                                     const float* __restrict__ Wv, const float* __restrict__ Wo,
                                                     u16* __restrict__ WT) {
  __shared__ u16 tile[64][72];
  int which = blockIdx.y;
  const float* W = (which == 0) ? Wq : (which == 1) ? Wk : (which == 2) ? Wv : Wo;
  u16* out = WT + (size_t)which * CC * CC;
  int tr = (blockIdx.x >> 4) * 64, tc = (blockIdx.x & 15) * 64;
#pragma unroll
  for (int i = 0; i < 16; ++i) {
    int e = i * 256 + threadIdx.x;
    int r = e >> 6, c = e & 63;
    tile[r][c] = f2bf(W[(size_t)(tr + r) * CC + tc + c]);
  }
  __syncthreads();
#pragma unroll
  for (int i = 0; i < 16; ++i) {
    int e = i * 256 + threadIdx.x;
    int cc2 = e >> 6, rr = e & 63;
    out[(size_t)(tc + cc2) * CC + tr + rr] = tile[rr][cc2];
  }
}

// ---------------- QKV projection GEMM ----------------
__global__ __launch_bounds__(256, 2) void k_qkv_gemm(
    const u16* __restrict__ xb, const u16* __restrict__ WTall,
    const float* __restrict__ bq, const float* __restrict__ bk, const float* __restrict__ bv,
    u16* __restrict__ Qw, u16* __restrict__ Kw, u16* __restrict__ Vtw) {
  __shared__ u16 Al[2][128 * 32];
  __shared__ u16 Bl[2][128 * 32];
  int p = blockIdx.y;
  const u16* WT = WTall + (size_t)p * (CC * CC);
  const float* bias = (p == 0) ? bq : (p == 1) ? bk : bv;
  int m0 = (blockIdx.x >> 3) * 128;
  int n0 = (blockIdx.x & 7) * 128;
  int tid = threadIdx.x;
  int lane = tid & 63, wave = tid >> 6;
  int wr = wave >> 1, wc = wave & 1;

  float4v acc[4][4];
#pragma unroll
  for (int i = 0; i < 4; ++i)
#pragma unroll
    for (int j = 0; j < 4; ++j) acc[i][j] = float4v{0.f, 0.f, 0.f, 0.f};

  auto stage = [&](int buf, int kt) {
    int k0 = kt * 32;
#pragma unroll
    for (int it = 0; it < 2; ++it) {
      int fc = tid + it * 256;
      int r = fc >> 2, c = fc & 3;
      int cg = c ^ ((r >> 1) & 3);
      const u16* gA = xb + (size_t)(m0 + r) * CC + k0 + cg * 8;
      const u16* gB = WT + (size_t)(n0 + r) * CC + k0 + cg * 8;
      char* lA = (char*)&Al[buf][0] + (wave * 64 + it * 256) * 16;
      char* lB = (char*)&Bl[buf][0] + (wave * 64 + it * 256) * 16;
      gld_lds16(gA, lA);
      gld_lds16(gB, lB);
    }
  };

  stage(0, 0);
  __syncthreads();
  int buf = 0;
  for (int kt = 0; kt < 32; ++kt) {
    if (kt + 1 < 32) stage(buf ^ 1, kt + 1);
    short8 af[4], bfr[4];
#pragma unroll
    for (int mf = 0; mf < 4; ++mf) {
      int row = wr * 64 + mf * 16 + (lane & 15);
      int cs = (lane >> 4) ^ ((row >> 1) & 3);
      af[mf] = *(const short8*)((const char*)&Al[buf][0] + row * 64 + cs * 16);
    }
#pragma unroll
    for (int nf = 0; nf < 4; ++nf) {
      int row = wc * 64 + nf * 16 + (lane & 15);
      int cs = (lane >> 4) ^ ((row >> 1) & 3);
      bfr[nf] = *(const short8*)((const char*)&Bl[buf][0] + row * 64 + cs * 16);
    }
#pragma unroll
    for (int mf = 0; mf < 4; ++mf)
#pragma unroll
      for (int nf = 0; nf < 4; ++nf)
        acc[mf][nf] = __builtin_amdgcn_mfma_f32_16x16x32_bf16(af[mf], bfr[nf], acc[mf][nf], 0, 0, 0);
    __syncthreads();
    buf ^= 1;
  }

  const float QSCALE = 0.125f * 1.44269504088896340736f;
#pragma unroll
  for (int mf = 0; mf < 4; ++mf) {
#pragma unroll
    for (int nf = 0; nf < 4; ++nf) {
      int n = n0 + wc * 64 + nf * 16 + (lane & 15);
      float bval = bias[n];
      int rowBase = wr * 64 + mf * 16 + (lane >> 4) * 4;
      int m_ = m0 + rowBase;
      int b_ = m_ >> 11, t_ = m_ & 2047;
      int h_ = n >> 6, dd = n & 63;
      if (p == 2) {
        ushort4v pk;
#pragma unroll
        for (int i = 0; i < 4; ++i) pk[i] = f2bf(acc[mf][nf][i] + bval);
        *(ushort4v*)(Vtw + ((size_t)(b_ * HH + h_) * DD + dd) * TT + t_) = pk;
      } else {
        u16* outp = (p == 0) ? Qw : Kw;
        float s = (p == 0) ? QSCALE : 1.0f;
#pragma unroll
        for (int i = 0; i < 4; ++i) {
          outp[((size_t)(b_ * HH + h_) * TT + (t_ + i)) * DD + dd] = f2bf((acc[mf][nf][i] + bval) * s);
        }
      }
    }
  }
}

// ---------------- flash attention (causal), v5 ----------------
// v2-v4 post-mortem: L2 request-rate bound (16B/lane scattered K/V frag
// loads = 16-32 line-requests per instr; ~18M total). v5: coalesced
// global_load_lds staging of K and Vt 64x64 tiles (XOR-swizzled source,
// involution on ds_read; rule #21), swapped 32x32x16 MFMAs so each lane
// owns one q-column: softmax = 31 local fmax + 1 shfl_xor(32), P stays
// in-register (cvt_pk + 2 shfl/slice exchange, T12 variant). One barrier
// per kv-tile, stage(t+1) in flight under compute(t). Grid: 32 bh x 32
// q64-tiles, heavy-first (u descending) + XCD-pinned heads.
__global__ __launch_bounds__(128, 2) void k_attn(
    const u16* __restrict__ Qw, const u16* __restrict__ Kw,
    const u16* __restrict__ Vtw, u16* __restrict__ Ow) {
  __shared__ u16 Klds[2][64 * 64];
  __shared__ u16 Vlds[2][64 * 64];
  int bid = blockIdx.x;
  int xcd = bid & 7, rank = bid >> 3;
  int bh = xcd + ((rank & 3) << 3);     // 4 heads per XCD -> K/V L2-resident
  int u = 31 - (rank >> 2);             // heavy q-tiles first
  int tid = threadIdx.x, lane = tid & 63, wave = tid >> 6;
  int l31 = lane & 31, hi = lane >> 5;
  int b_ = bh >> 4, h_ = bh & 15;
  const u16* Qbase = Qw + (size_t)bh * TT * DD;
  const u16* Kbase = Kw + (size_t)bh * TT * DD;
  const u16* Vbase = Vtw + (size_t)bh * DD * TT;
  int qw = u * 64 + wave * 32;
  int nt = u + 1;

  // Q fragments (B-operand): col=q=l31, k-slice d = 16*ks + 8*hi + e
  short8 qf[4];
#pragma unroll
  for (int ks = 0; ks < 4; ++ks)
    qf[ks] = *(const short8*)(Qbase + (size_t)(qw + l31) * DD + ks * 16 + hi * 8);

  int sr = tid >> 3;                    // 0..15: row-in-round
  int sc = tid & 7;                     // 16B chunk 0..7

  f32x16 acc0, acc1;
#pragma unroll
  for (int r = 0; r < 16; ++r) { acc0[r] = 0.f; acc1[r] = 0.f; }
  float mrun = -1e30f, lrun = 0.f;

  auto stageKV = [&](int t, int buf) {
    int kv0 = t * 64;
#pragma unroll
    for (int rd = 0; rd < 4; ++rd) {
      int r = rd * 16 + sr;
      int cg = sc ^ (r & 7);
      const u16* gK = Kbase + (size_t)(kv0 + r) * DD + cg * 8;
      const u16* gV = Vbase + (size_t)r * TT + kv0 + cg * 8;
      char* lK = (char*)&Klds[buf][0] + (rd * 128 + wave * 64) * 16;
      char* lV = (char*)&Vlds[buf][0] + (rd * 128 + wave * 64) * 16;
      gld_lds16(gK, lK);
      gld_lds16(gV, lV);
    }
  };

  stageKV(0, 0);
  int buf = 0;
  for (int t = 0; t < nt; ++t) {
    __syncthreads();                    // stage(t) visible; buf^1 readers done
    if (t + 1 < nt) stageKV(t + 1, buf ^ 1);
    int kv0 = t * 64;
    const char* Kb = (const char*)&Klds[buf][0];
    const char* Vb = (const char*)&Vlds[buf][0];
    int swz = (l31 & 7);

    // S = K * Q^T (swapped): lane holds q=l31; rows kv = 8m+4hi+j (+32 for s1)
    f32x16 s0, s1;
#pragma unroll
    for (int r = 0; r < 16; ++r) { s0[r] = 0.f; s1[r] = 0.f; }
#pragma unroll
    for (int ks = 0; ks < 4; ++ks) {
      short8 kf = *(const short8*)(Kb + l31 * 128 + ((2 * ks + hi) ^ swz) * 16);
      s0 = __builtin_amdgcn_mfma_f32_32x32x16_bf16(kf, qf[ks], s0, 0, 0, 0);
    }
#pragma unroll
    for (int ks = 0; ks < 4; ++ks) {
      short8 kf = *(const short8*)(Kb + (l31 + 32) * 128 + ((2 * ks + hi) ^ swz) * 16);
      s1 = __builtin_amdgcn_mfma_f32_32x32x16_bf16(kf, qf[ks], s1, 0, 0, 0);
    }

    if (kv0 + 63 > qw) {
      int qg = qw + l31;
#pragma unroll
      for (int r = 0; r < 16; ++r) {
        int kvg = kv0 + 8 * (r >> 2) + 4 * hi + (r & 3);
        if (kvg > qg) s0[r] = -1e30f;
        if (kvg + 32 > qg) s1[r] = -1e30f;
      }
    }

    // row max: 31 local fmax + 1 exchange
    float pm = -1e30f;
#pragma unroll
    for (int r = 0; r < 16; ++r) pm = fmaxf(pm, s0[r]);
#pragma unroll
    for (int r = 0; r < 16; ++r) pm = fmaxf(pm, s1[r]);
    pm = fmaxf(pm, __shfl_xor(pm, 32));

    if (__any(pm > mrun + 8.f)) {       // defer-max (T13)
      float mn = fmaxf(mrun, pm);
      float sc_ = __builtin_exp2f(mrun - mn);
      mrun = mn; lrun *= sc_;
#pragma unroll
      for (int r = 0; r < 16; ++r) { acc0[r] *= sc_; acc1[r] *= sc_; }
    }

    // P = exp2(S - m), in place; row sum
    float rs = 0.f;
#pragma unroll
    for (int r = 0; r < 16; ++r) { s0[r] = __builtin_exp2f(s0[r] - mrun); rs += s0[r]; }
#pragma unroll
    for (int r = 0; r < 16; ++r) { s1[r] = __builtin_exp2f(s1[r] - mrun); rs += s1[r]; }
    rs += __shfl_xor(rs, 32);
    lrun += rs;

    // pack to bf16 pairs: pkX[m] = {j01, j23} for rows 8m+4hi+j
    uint32_t pk0[4][2], pk1[4][2];
#pragma unroll
    for (int m = 0; m < 4; ++m) {
      pk0[m][0] = cvtpk(s0[4 * m + 0], s0[4 * m + 1]);
      pk0[m][1] = cvtpk(s0[4 * m + 2], s0[4 * m + 3]);
      pk1[m][0] = cvtpk(s1[4 * m + 0], s1[4 * m + 1]);
      pk1[m][1] = cvtpk(s1[4 * m + 2], s1[4 * m + 3]);
    }

    // per 16-kv slice: exchange halves with lane^32, build P B-frag, PV MFMA
#define SLICE(PK, Q1, VS)                                                     \
    {                                                                         \
      uint32_t k0 = hi ? PK[2 * Q1 + 1][0] : PK[2 * Q1][0];                   \
      uint32_t k1 = hi ? PK[2 * Q1 + 1][1] : PK[2 * Q1][1];                   \
      uint32_t t0 = hi ? PK[2 * Q1][0] : PK[2 * Q1 + 1][0];                   \
      uint32_t t1 = hi ? PK[2 * Q1][1] : PK[2 * Q1 + 1][1];                   \
      uint32_t r0 = (uint32_t)__shfl_xor((int)t0, 32);                        \
      uint32_t r1 = (uint32_t)__shfl_xor((int)t1, 32);                        \
      union { uint32_t u[4]; short8 v; } pw;                                  \
      pw.u[0] = hi ? r0 : k0; pw.u[1] = hi ? r1 : k1;                         \
      pw.u[2] = hi ? k0 : r0; pw.u[3] = hi ? k1 : r1;                         \
      short8 vf0 = *(const short8*)(Vb + l31 * 128 + ((2 * VS + hi) ^ swz) * 16);       \
      short8 vf1 = *(const short8*)(Vb + (l31 + 32) * 128 + ((2 * VS + hi) ^ swz) * 16);\
      acc0 = __builtin_amdgcn_mfma_f32_32x32x16_bf16(vf0, pw.v, acc0, 0, 0, 0);         \
      acc1 = __builtin_amdgcn_mfma_f32_32x32x16_bf16(vf1, pw.v, acc1, 0, 0, 0);         \
    }
    SLICE(pk0, 0, 0)
    SLICE(pk0, 1, 1)
    SLICE(pk1, 0, 2)
    SLICE(pk1, 1, 3)
#undef SLICE
    buf ^= 1;
  }

  // epilogue: normalize, store (lane q = l31; d = 32*df + 8m + 4hi + j)
  float inv = 1.f / lrun;
  int t_ = qw + l31;
  u16* orow = Ow + ((size_t)(b_ * TT + t_)) * CC + h_ * DD;
#pragma unroll
  for (int m = 0; m < 4; ++m) {
    ushort4v p0, p1;
#pragma unroll
    for (int j = 0; j < 4; ++j) {
      p0[j] = f2bf(acc0[4 * m + j] * inv);
      p1[j] = f2bf(acc1[4 * m + j] * inv);
    }
    *(ushort4v*)(orow + 8 * m + 4 * hi) = p0;
    *(ushort4v*)(orow + 32 + 8 * m + 4 * hi) = p1;
  }
}

// ---------------- output projection GEMM (bf16 in, fp32 out) ----------------
__global__ __launch_bounds__(256, 2) void k_out_gemm(
    const u16* __restrict__ Ob, const u16* __restrict__ WoT,
    const float* __restrict__ bo, float* __restrict__ out) {
  __shared__ u16 Al[2][128 * 32];
  __shared__ u16 Bl[2][128 * 32];
  int m0 = (blockIdx.x >> 3) * 128;
  int n0 = (blockIdx.x & 7) * 128;
  int tid = threadIdx.x;
  int lane = tid & 63, wave = tid >> 6;
  int wr = wave >> 1, wc = wave & 1;

  float4v acc[4][4];
#pragma unroll
  for (int i = 0; i < 4; ++i)
#pragma unroll
    for (int j = 0; j < 4; ++j) acc[i][j] = float4v{0.f, 0.f, 0.f, 0.f};

  auto stage = [&](int buf, int kt) {
    int k0 = kt * 32;
#pragma unroll
    for (int it = 0; it < 2; ++it) {
      int fc = tid + it * 256;
      int r = fc >> 2, c = fc & 3;
      int cg = c ^ ((r >> 1) & 3);
      const u16* gA = Ob + (size_t)(m0 + r) * CC + k0 + cg * 8;
      const u16* gB = WoT + (size_t)(n0 + r) * CC + k0 + cg * 8;
      char* lA = (char*)&Al[buf][0] + (wave * 64 + it * 256) * 16;
      char* lB = (char*)&Bl[buf][0] + (wave * 64 + it * 256) * 16;
      gld_lds16(gA, lA);
      gld_lds16(gB, lB);
    }
  };

  stage(0, 0);
  __syncthreads();
  int buf = 0;
  for (int kt = 0; kt < 32; ++kt) {
    if (kt + 1 < 32) stage(buf ^ 1, kt + 1);
    short8 af[4], bfr[4];
#pragma unroll
    for (int mf = 0; mf < 4; ++mf) {
      int row = wr * 64 + mf * 16 + (lane & 15);
      int cs = (lane >> 4) ^ ((row >> 1) & 3);
      af[mf] = *(const short8*)((const char*)&Al[buf][0] + row * 64 + cs * 16);
    }
#pragma unroll
    for (int nf = 0; nf < 4; ++nf) {
      int row = wc * 64 + nf * 16 + (lane & 15);
      int cs = (lane >> 4) ^ ((row >> 1) & 3);
      bfr[nf] = *(const short8*)((const char*)&Bl[buf][0] + row * 64 + cs * 16);
    }
#pragma unroll
    for (int mf = 0; mf < 4; ++mf)
#pragma unroll
      for (int nf = 0; nf < 4; ++nf)
        acc[mf][nf] = __builtin_amdgcn_mfma_f32_16x16x32_bf16(af[mf], bfr[nf], acc[mf][nf], 0, 0, 0);
    __syncthreads();
    buf ^= 1;
  }

#pragma unroll
  for (int mf = 0; mf < 4; ++mf)
#pragma unroll
    for (int nf = 0; nf < 4; ++nf) {
      int n = n0 + wc * 64 + nf * 16 + (lane & 15);
      float bval = bo[n];
      int rowBase = m0 + wr * 64 + mf * 16 + (lane >> 4) * 4;
#pragma unroll
      for (int i = 0; i < 4; ++i)
        out[(size_t)(rowBase + i) * CC + n] = acc[mf][nf][i] + bval;
    }
}

extern "C" void kernel_launch(void* const* d_in, const int* in_sizes, int n_in,
                              void* d_out, int out_size, void* d_ws, size_t ws_size,
                              hipStream_t stream) {
  const float* x  = (const float*)d_in[0];
  const float* Wq = (const float*)d_in[1];
  const float* bq = (const float*)d_in[2];
  const float* Wk = (const float*)d_in[3];
  const float* bk = (const float*)d_in[4];
  const float* Wv = (const float*)d_in[5];
  const float* bv = (const float*)d_in[6];
  const float* Wo = (const float*)d_in[7];
  const float* bo = (const float*)d_in[8];
  float* out = (float*)d_out;
  char* ws = (char*)d_ws;
  if (ws_size < (size_t)50331648) return;  // need 48 MB scratch

  u16* xb  = (u16*)(ws);                    // 8 MB
  u16* WT  = (u16*)(ws + 8388608);          // 4 x 2 MB (WqT,WkT,WvT,WoT)
  u16* Qw  = (u16*)(ws + 16777216);         // 8 MB  [b,h,t,d]
  u16* Kw  = (u16*)(ws + 25165824);         // 8 MB  [b,h,t,d]
  u16* Vtw = (u16*)(ws + 33554432);         // 8 MB  [b,h,d,t]
  u16* Ob  = (u16*)(ws + 41943040);         // 8 MB  [b*t, c]

  hipLaunchKernelGGL(k_convert_x, dim3(4096), dim3(256), 0, stream, x, xb);
  hipLaunchKernelGGL(k_transpose_w, dim3(256, 4), dim3(256), 0, stream, Wq, Wk, Wv, Wo, WT);
  hipLaunchKernelGGL(k_qkv_gemm, dim3(256, 3), dim3(256), 0, stream,
                     xb, WT, bq, bk, bv, Qw, Kw, Vtw);
  hipLaunchKernelGGL(k_attn, dim3(1024), dim3(128), 0, stream, Qw, Kw, Vtw, Ob);
  hipLaunchKernelGGL(k_out_gemm, dim3(256), dim3(256), 0, stream,
                     Ob, WT + 3 * 1048576, bo, out);
}